// Round 5
// baseline (9741.135 us; speedup 1.0000x reference)
//
#include <hip/hip_runtime.h>
#include <math.h>

#define HID   256
#define GATES 1024   // 4*HID
#define BATCH 64
#define SEQ   2048

typedef __attribute__((ext_vector_type(8))) short short8;
typedef __attribute__((ext_vector_type(4))) float f32x4;

// ---------------------------------------------------------------------------
// GEMM: out[r][g] = sum_k A_row(r)[k] * W[g][k] + bias[g]   (unchanged)
// ---------------------------------------------------------------------------
#define BM 128
#define BN 128
#define BK 16
#define LDP 132

__global__ __launch_bounds__(256, 2)
void xg_gemm(const float* __restrict__ A, const float* __restrict__ W,
             const float* __restrict__ bias, float* __restrict__ out,
             int a_bstride, int ch_log2)
{
    __shared__ float As[BK][LDP];
    __shared__ float Ws[BK][LDP];

    const int tid   = threadIdx.x;
    const int m_blk = blockIdx.x * BM;
    const int n_blk = blockIdx.y * BN;

    const int tn = (tid & 15) * 4;
    const int tm = (tid >> 4) * 4;

    float acc[8][8];
    #pragma unroll
    for (int i = 0; i < 8; ++i)
        #pragma unroll
        for (int j = 0; j < 8; ++j) acc[i][j] = 0.f;

    const int lrow = tid >> 2;
    const int lkc  = (tid & 3) * 4;
    const int CHm1 = (1 << ch_log2) - 1;

    for (int k0 = 0; k0 < HID; k0 += BK) {
        #pragma unroll
        for (int p = 0; p < 2; ++p) {
            int row = p * 64 + lrow;
            int r   = m_blk + row;
            int b   = r >> ch_log2;
            int t   = r & CHm1;
            const float4 a = *(const float4*)(A + (size_t)b * a_bstride +
                                              (size_t)t * HID + k0 + lkc);
            As[lkc + 0][row] = a.x;
            As[lkc + 1][row] = a.y;
            As[lkc + 2][row] = a.z;
            As[lkc + 3][row] = a.w;

            int g = n_blk + row;
            const float4 w = *(const float4*)(W + (size_t)g * HID + k0 + lkc);
            Ws[lkc + 0][row] = w.x;
            Ws[lkc + 1][row] = w.y;
            Ws[lkc + 2][row] = w.z;
            Ws[lkc + 3][row] = w.w;
        }
        __syncthreads();

        #pragma unroll
        for (int kk = 0; kk < BK; ++kk) {
            float4 a0 = *(const float4*)&As[kk][tm];
            float4 a1 = *(const float4*)&As[kk][tm + 64];
            float4 b0 = *(const float4*)&Ws[kk][tn];
            float4 b1 = *(const float4*)&Ws[kk][tn + 64];
            float av[8] = {a0.x, a0.y, a0.z, a0.w, a1.x, a1.y, a1.z, a1.w};
            float bv[8] = {b0.x, b0.y, b0.z, b0.w, b1.x, b1.y, b1.z, b1.w};
            #pragma unroll
            for (int i = 0; i < 8; ++i)
                #pragma unroll
                for (int j = 0; j < 8; ++j)
                    acc[i][j] += av[i] * bv[j];
        }
        __syncthreads();
    }

    const float4 bias0 = *(const float4*)&bias[n_blk + tn];
    const float4 bias1 = *(const float4*)&bias[n_blk + tn + 64];
    #pragma unroll
    for (int i = 0; i < 8; ++i) {
        int m  = (i < 4) ? (tm + i) : (tm + 60 + i);
        int gm = m_blk + m;
        float* op = out + (size_t)gm * GATES + n_blk;
        float4 v0 = {acc[i][0] + bias0.x, acc[i][1] + bias0.y,
                     acc[i][2] + bias0.z, acc[i][3] + bias0.w};
        float4 v1 = {acc[i][4] + bias1.x, acc[i][5] + bias1.y,
                     acc[i][6] + bias1.z, acc[i][7] + bias1.w};
        *(float4*)(op + tn)      = v0;
        *(float4*)(op + tn + 64) = v1;
    }
}

// ---------------------------------------------------------------------------
// Cooperative recurrence v4: MFMA compensated-bf16 matvec.
// Same skeleton as R4 (256 wgs = 4 slices x 64 batch, 512 thr, single-atom
// parity mailbox, 2 barriers/step). The matvec W[256x256]·h is done with
// mfma_f32_16x16x32_bf16: w = w_hi + w_lo, h = h_hi + h_lo (bf16 splits),
// acc += hi·hi + hi·lo + lo·hi  (fp32 acc; dropped lo·lo ~ 2^-18 rel).
// Wave w owns local rows w*32..w*32+31 (2 m-tiles); B replicates h over all
// 16 N-cols, so every lane ends up holding y for rows quad*4+reg.
// A-frag layout (verified m120): A[m=lane&15][k=(lane>>4)*8+j].
// ---------------------------------------------------------------------------
#define MBSTRIDE ((size_t)BATCH * HID)   // ulongs per parity block

__device__ __forceinline__ float sigmoid_f(float x) {
    return 1.f / (1.f + __expf(-x));
}
__device__ __forceinline__ float tanh_f(float x) {
    return 1.f - 2.f / (1.f + __expf(2.f * x));
}
__device__ __forceinline__ unsigned short f2bf_rne(float f) {
    unsigned u = __float_as_uint(f);
    u = u + 0x7FFFu + ((u >> 16) & 1u);
    return (unsigned short)(u >> 16);
}
__device__ __forceinline__ float bf2f(unsigned short b) {
    return __uint_as_float(((unsigned)b) << 16);
}

__global__ __launch_bounds__(512, 2)
void lstm_rec_coop(const float* __restrict__ xg, const float* __restrict__ w_hh,
                   const float* __restrict__ b_hh, unsigned long long* mbox,
                   float* __restrict__ c_state, float* __restrict__ h_out,
                   int CH, int gbase)
{
    __shared__ __attribute__((aligned(16))) unsigned short hh_hi[HID];
    __shared__ __attribute__((aligned(16))) unsigned short hh_lo[HID];
    __shared__ __attribute__((aligned(16))) float g_s[256];

    const int s    = blockIdx.x >> 6;
    const int b    = blockIdx.x & 63;
    const int tid  = threadIdx.x;
    const int lane = tid & 63;
    const int wv   = tid >> 6;          // wave 0..7
    const int quad = lane >> 4;         // 0..3
    const int mcol = lane & 15;
    const int qoff = quad * 8;          // k-offset within a 32-k-tile

    // ---- one-time: gather + split weights into pinned A-fragments ----
    // frag (tile,kt): rows wv*32+tile*16+mcol, k = kt*32 + quad*8 + j (j=0..7)
    short8 wa_hi[2][8], wa_lo[2][8];
    #pragma unroll
    for (int tile = 0; tile < 2; ++tile) {
        const int lrow = wv * 32 + tile * 16 + mcol;
        const int grow = (lrow >> 6) * 256 + s * 64 + (lrow & 63);
        const float* wrow = w_hh + (size_t)grow * HID;
        #pragma unroll
        for (int kt = 0; kt < 8; ++kt) {
            const float* wp = wrow + kt * 32 + qoff;
            float4 w0 = *(const float4*)wp;
            float4 w1 = *(const float4*)(wp + 4);
            float wf[8] = {w0.x, w0.y, w0.z, w0.w, w1.x, w1.y, w1.z, w1.w};
            short8 hi, lo;
            #pragma unroll
            for (int j = 0; j < 8; ++j) {
                unsigned short hb = f2bf_rne(wf[j]);
                hi[j] = (short)hb;
                lo[j] = (short)f2bf_rne(wf[j] - bf2f(hb));
            }
            wa_hi[tile][kt] = hi;
            wa_lo[tile][kt] = lo;
        }
    }
    // forbid sinking the weight loads/conversions into the t-loop
    asm volatile("" ::: "memory");

    // ---- one-time: per-unit state & biases (threads 0..63 own units) ----
    float c_u = 0.f, bh_i = 0.f, bh_f = 0.f, bh_g = 0.f, bh_o = 0.f;
    if (tid < 64) {
        c_u  = c_state[b * HID + s * 64 + tid];
        bh_i = b_hh[          s * 64 + tid];
        bh_f = b_hh[HID     + s * 64 + tid];
        bh_g = b_hh[2 * HID + s * 64 + tid];
        bh_o = b_hh[3 * HID + s * 64 + tid];
    }

    const float* xg_b = xg + (size_t)b * CH * GATES;

    for (int t = 0; t < CH; ++t) {
        const int gt = gbase + t;

        // ---- xg prefetch: issue before the spin so latency hides under it --
        float x_i = 0.f, x_f = 0.f, x_g = 0.f, x_o = 0.f;
        if (tid < 64) {
            const size_t xo = (size_t)t * GATES + s * 64 + tid;
            x_i = xg_b[xo];
            x_f = xg_b[xo + 256];
            x_g = xg_b[xo + 512];
            x_o = xg_b[xo + 768];
        }

        // ---- poll mailbox, split h(t-1) into bf16 hi/lo in LDS ----
        if (tid < HID) {
            const unsigned long long* slot =
                mbox + (size_t)(gt & 1) * MBSTRIDE + b * HID + tid;
            unsigned long long w;
            do {
                w = __hip_atomic_load(slot, __ATOMIC_RELAXED,
                                      __HIP_MEMORY_SCOPE_AGENT);
            } while ((unsigned)(w >> 32) != (unsigned)gt);
            float hv = __uint_as_float((unsigned)w);
            unsigned short hb = f2bf_rne(hv);
            hh_hi[tid] = hb;
            hh_lo[tid] = f2bf_rne(hv - bf2f(hb));
        }
        __syncthreads();   // hh ready; D(t-1) done with g_s

        // ---- MFMA matvec: 2 m-tiles x 8 k-tiles x 3 compensation terms ----
        {
            f32x4 acc0 = {0.f, 0.f, 0.f, 0.f};
            f32x4 acc1 = {0.f, 0.f, 0.f, 0.f};
            #pragma unroll
            for (int kt = 0; kt < 8; ++kt) {
                short8 bhi = *(const short8*)&hh_hi[kt * 32 + qoff];
                short8 blo = *(const short8*)&hh_lo[kt * 32 + qoff];
                acc0 = __builtin_amdgcn_mfma_f32_16x16x32_bf16(
                           wa_hi[0][kt], bhi, acc0, 0, 0, 0);
                acc1 = __builtin_amdgcn_mfma_f32_16x16x32_bf16(
                           wa_hi[1][kt], bhi, acc1, 0, 0, 0);
                acc0 = __builtin_amdgcn_mfma_f32_16x16x32_bf16(
                           wa_hi[0][kt], blo, acc0, 0, 0, 0);
                acc1 = __builtin_amdgcn_mfma_f32_16x16x32_bf16(
                           wa_hi[1][kt], blo, acc1, 0, 0, 0);
                acc0 = __builtin_amdgcn_mfma_f32_16x16x32_bf16(
                           wa_lo[0][kt], bhi, acc0, 0, 0, 0);
                acc1 = __builtin_amdgcn_mfma_f32_16x16x32_bf16(
                           wa_lo[1][kt], bhi, acc1, 0, 0, 0);
            }
            // C/D: col=lane&15, row=quad*4+reg; all cols identical (h replicated)
            if (mcol == 0) {
                *(f32x4*)&g_s[wv * 32 +      quad * 4] = acc0;
                *(f32x4*)&g_s[wv * 32 + 16 + quad * 4] = acc1;
            }
        }
        __syncthreads();   // g_s ready

        // ---- unit update + publish (gate order i,f,g,o) ----
        if (tid < 64) {
            float gi = g_s[tid]       + x_i + bh_i;
            float gf = g_s[64 + tid]  + x_f + bh_f;
            float gg = g_s[128 + tid] + x_g + bh_g;
            float go = g_s[192 + tid] + x_o + bh_o;
            float ig = sigmoid_f(gi);
            float fg = sigmoid_f(gf);
            float gv = tanh_f(gg);
            float og = sigmoid_f(go);
            c_u = fg * c_u + ig * gv;
            float h = og * tanh_f(c_u);

            unsigned long long wpk =
                ((unsigned long long)(unsigned)(gt + 1) << 32) |
                (unsigned long long)__float_as_uint(h);
            __hip_atomic_store(
                mbox + (size_t)((gt + 1) & 1) * MBSTRIDE + b * HID + s * 64 + tid,
                wpk, __ATOMIC_RELAXED, __HIP_MEMORY_SCOPE_AGENT);

            if (h_out) h_out[((size_t)b * CH + t) * HID + s * 64 + tid] = h;
        }
        // no barrier here: next sync1 separates stage(t+1) from readers of t
    }

    if (tid < 64) c_state[b * HID + s * 64 + tid] = c_u;
}

// ---------------------------------------------------------------------------
__global__ void final_linear(const unsigned long long* __restrict__ hw,
                             const float* __restrict__ w_lin,
                             const float* __restrict__ b_lin,
                             float* __restrict__ out)
{
    int b = blockIdx.x;
    int l = threadIdx.x;
    float p = 0.f;
    #pragma unroll
    for (int j = 0; j < 4; ++j) {
        int u = l + j * 64;
        p += __uint_as_float((unsigned)hw[b * HID + u]) * w_lin[u];
    }
    #pragma unroll
    for (int off = 32; off > 0; off >>= 1) p += __shfl_down(p, off, 64);
    if (l == 0) out[b] = p + b_lin[0];
}

// ---------------------------------------------------------------------------
extern "C" void kernel_launch(void* const* d_in, const int* in_sizes, int n_in,
                              void* d_out, int out_size, void* d_ws, size_t ws_size,
                              hipStream_t stream)
{
    const float* input = (const float*)d_in[0];
    const float* w_ih  = (const float*)d_in[1];
    const float* w_hh  = (const float*)d_in[2];
    const float* b_ih  = (const float*)d_in[3];
    const float* b_hh  = (const float*)d_in[4];
    const float* w_lin = (const float*)d_in[5];
    const float* b_lin = (const float*)d_in[6];
    float* out = (float*)d_out;

    const size_t c_elems  = (size_t)BATCH * HID;
    const size_t mb_bytes = 2 * MBSTRIDE * sizeof(unsigned long long);
    char*  ws   = (char*)d_ws;
    float* c1st = (float*)ws;
    float* c2st = c1st + c_elems;
    unsigned long long* mb1 = (unsigned long long*)(c2st + c_elems);
    unsigned long long* mb2 = mb1 + 2 * MBSTRIDE;
    const size_t zero_bytes = 2 * c_elems * 4 + 2 * mb_bytes;
    float* big  = (float*)(ws + ((zero_bytes + 255) & ~(size_t)255));

    int CH = 128;
    while (CH > 16) {
        size_t need = ((zero_bytes + 255) & ~(size_t)255)
                    + ((size_t)2 * BATCH * CH * GATES + (size_t)BATCH * CH * HID) * 4;
        if (need <= ws_size) break;
        CH >>= 1;
    }
    const int ch_log2 = __builtin_ctz((unsigned)CH);

    float* xg1  = big;
    float* xg2  = xg1 + (size_t)BATCH * CH * GATES;
    float* h1ch = xg2 + (size_t)BATCH * CH * GATES;

    hipMemsetAsync(ws, 0, zero_bytes, stream);

    const int NC = SEQ / CH;
    dim3 gblk(BATCH * CH / BM, GATES / BN);

    for (int c = 0; c < NC; ++c) {
        xg_gemm<<<gblk, 256, 0, stream>>>(input + (size_t)c * CH * HID, w_ih,
                                          b_ih, xg1, SEQ * HID, ch_log2);
        lstm_rec_coop<<<256, 512, 0, stream>>>(xg1, w_hh, b_hh, mb1,
                                               c1st, h1ch, CH, c * CH);
        xg_gemm<<<gblk, 256, 0, stream>>>(h1ch, w_ih + GATES * HID,
                                          b_ih + GATES, xg2, CH * HID, ch_log2);
        lstm_rec_coop<<<256, 512, 0, stream>>>(xg2, w_hh + (size_t)GATES * HID,
                                               b_hh + GATES, mb2,
                                               c2st, nullptr, CH, c * CH);
    }

    final_linear<<<BATCH, 64, 0, stream>>>(mb2, w_lin, b_lin, out);
}